// Round 5
// baseline (281.750 us; speedup 1.0000x reference)
//
#include <hip/hip_runtime.h>
#include <math.h>

#define SS 2048
#define DD 1280
#define HH 16
#define HDD 80
#define ND3 3840

typedef __attribute__((ext_vector_type(8))) short short8;
typedef __attribute__((ext_vector_type(4))) short s16x4;
typedef __attribute__((ext_vector_type(4))) float f32x4;

__device__ inline short f2bf(float f) {
    union { float f; unsigned u; } x; x.f = f;
    unsigned r = x.u + 0x7FFF + ((x.u >> 16) & 1);
    return (short)(r >> 16);
}
__device__ inline float bf2f(short s) {
    union { unsigned u; float f; } x; x.u = ((unsigned)(unsigned short)s) << 16;
    return x.f;
}

// ---------------- fused split: three fp32 arrays -> (hi, lo) bf16 ----------------
// block ranges: [0, nbA) -> a, [nbA, nbA+nbB) -> b, rest -> c. All sizes /1024 exact.
__global__ __launch_bounds__(256) void split3(
    const float* __restrict__ a, short* __restrict__ ah, short* __restrict__ al, int nbA,
    const float* __restrict__ b, short* __restrict__ bh, short* __restrict__ bl, int nbB,
    const float* __restrict__ c, short* __restrict__ ch, short* __restrict__ cl)
{
    const float* x; short* h; short* l;
    int blk = blockIdx.x;
    if (blk < nbA)            { x = a; h = ah; l = al; }
    else if (blk < nbA + nbB) { blk -= nbA; x = b; h = bh; l = bl; }
    else                      { blk -= nbA + nbB; x = c; h = ch; l = cl; }
    int i = (blk * 256 + threadIdx.x) * 4;
    float4 v = *(const float4*)(x + i);
    s16x4 hv, lv;
    float vv[4] = {v.x, v.y, v.z, v.w};
    #pragma unroll
    for (int t = 0; t < 4; ++t) {
        short hh = f2bf(vv[t]);
        hv[t] = hh;
        lv[t] = f2bf(vv[t] - bf2f(hh));
    }
    *(s16x4*)(h + i) = hv;
    *(s16x4*)(l + i) = lv;
}

// ---------------- bf16x3 MFMA GEMM: C = A @ B^T + bias ----------------
// Tile BMT x BNT, 4 waves (2x2). BMT in {64,128}, BNT in {64,128}.
#define LDSA(m, kg) ((m) * 32 + (((kg) ^ (((m) >> 1) & 3)) << 3))

template <int BMT, int BNT>
__global__ __launch_bounds__(256) void gemm_bf16x3(
    const short* __restrict__ Ah, const short* __restrict__ Al,
    const short* __restrict__ Bh, const short* __restrict__ Bl,
    const float* __restrict__ bias, float* __restrict__ C,
    int M, int N, int K)
{
    constexpr int IT = BMT / 32;        // m-tiles per wave
    constexpr int JT = BNT / 32;        // n-tiles per wave
    constexpr int AU = (BMT * 4) / 256; // A staging chunks per thread
    constexpr int BU = (BNT * 4) / 256; // B staging chunks per thread
    __shared__ short AhS[BMT * 32];
    __shared__ short AlS[BMT * 32];
    __shared__ short BhS[BNT * 32];
    __shared__ short BlS[BNT * 32];

    const int tid = threadIdx.x;
    const int w = tid >> 6;
    const int lane = tid & 63;
    const int l15 = lane & 15;
    const int quad = lane >> 4;
    const int wm = w >> 1, wn = w & 1;
    const int bm = blockIdx.y * BMT;
    const int bn = blockIdx.x * BNT;

    f32x4 acc[IT][JT];
    #pragma unroll
    for (int i = 0; i < IT; ++i)
        #pragma unroll
        for (int j = 0; j < JT; ++j)
            acc[i][j] = (f32x4){0.f, 0.f, 0.f, 0.f};

    short8 rah[AU], ral[AU], rbh[BU], rbl[BU];
    auto loadg = [&](int k0) {
        #pragma unroll
        for (int u = 0; u < AU; ++u) {
            int c = tid + u * 256, m = c >> 2, kg = c & 3;
            size_t off = (size_t)(bm + m) * K + k0 + kg * 8;
            rah[u] = *(const short8*)(Ah + off);
            ral[u] = *(const short8*)(Al + off);
        }
        #pragma unroll
        for (int u = 0; u < BU; ++u) {
            int c = tid + u * 256, m = c >> 2, kg = c & 3;
            size_t off = (size_t)(bn + m) * K + k0 + kg * 8;
            rbh[u] = *(const short8*)(Bh + off);
            rbl[u] = *(const short8*)(Bl + off);
        }
    };

    loadg(0);
    for (int k0 = 0; k0 < K; k0 += 32) {
        __syncthreads();
        #pragma unroll
        for (int u = 0; u < AU; ++u) {
            int c = tid + u * 256, m = c >> 2, kg = c & 3;
            *(short8*)&AhS[LDSA(m, kg)] = rah[u];
            *(short8*)&AlS[LDSA(m, kg)] = ral[u];
        }
        #pragma unroll
        for (int u = 0; u < BU; ++u) {
            int c = tid + u * 256, m = c >> 2, kg = c & 3;
            *(short8*)&BhS[LDSA(m, kg)] = rbh[u];
            *(short8*)&BlS[LDSA(m, kg)] = rbl[u];
        }
        __syncthreads();
        if (k0 + 32 < K) loadg(k0 + 32);

        short8 af[IT], alf[IT], bfh[JT], bfl[JT];
        #pragma unroll
        for (int i = 0; i < IT; ++i) {
            int m = wm * (BMT / 2) + i * 16 + l15;
            af[i]  = *(short8*)&AhS[LDSA(m, quad)];
            alf[i] = *(short8*)&AlS[LDSA(m, quad)];
        }
        #pragma unroll
        for (int j = 0; j < JT; ++j) {
            int n = wn * (BNT / 2) + j * 16 + l15;
            bfh[j] = *(short8*)&BhS[LDSA(n, quad)];
            bfl[j] = *(short8*)&BlS[LDSA(n, quad)];
        }
        #pragma unroll
        for (int i = 0; i < IT; ++i)
            #pragma unroll
            for (int j = 0; j < JT; ++j) {
                acc[i][j] = __builtin_amdgcn_mfma_f32_16x16x32_bf16(af[i],  bfh[j], acc[i][j], 0, 0, 0);
                acc[i][j] = __builtin_amdgcn_mfma_f32_16x16x32_bf16(af[i],  bfl[j], acc[i][j], 0, 0, 0);
                acc[i][j] = __builtin_amdgcn_mfma_f32_16x16x32_bf16(alf[i], bfh[j], acc[i][j], 0, 0, 0);
            }
    }

    #pragma unroll
    for (int j = 0; j < JT; ++j) {
        int col = bn + wn * (BNT / 2) + j * 16 + l15;
        float bb = bias[col];
        #pragma unroll
        for (int i = 0; i < IT; ++i)
            #pragma unroll
            for (int r = 0; r < 4; ++r) {
                int row = bm + wm * (BMT / 2) + i * 16 + quad * 4 + r;
                C[(size_t)row * N + col] = acc[i][j][r] + bb;
            }
    }
}

// ---------------- RoPE + scatter -> bf16 q (pre-scaled), k, v ----------------
__global__ __launch_bounds__(256) void rope_scatter_bf16(
    const float* __restrict__ qkv, const float* __restrict__ rpe,
    short* __restrict__ q, short* __restrict__ k, short* __restrict__ v)
{
    __shared__ float cs[40], sn[40];
    const int s = blockIdx.x;
    if (threadIdx.x < 40)
        __sincosf(rpe[s * 40 + threadIdx.x], &sn[threadIdx.x], &cs[threadIdx.x]);
    __syncthreads();
    const float scale = 0.11180339887498949f;  // 80^-0.5
    for (int j = threadIdx.x; j < ND3; j += 256) {
        int p = j / DD;
        int rem = j - p * DD;
        int hh = rem / HDD;
        int d = rem - hh * HDD;
        float x = qkv[(size_t)s * ND3 + j];
        float val;
        if (p == 2) {
            val = x;
        } else {
            int dm = (d < 40) ? d : d - 40;
            float other = (d < 40)
                ? -qkv[(size_t)s * ND3 + p * DD + hh * HDD + d + 40]
                :  qkv[(size_t)s * ND3 + p * DD + hh * HDD + d - 40];
            val = x * cs[dm] + other * sn[dm];
            if (p == 0) val *= scale;
        }
        short* dst = (p == 0) ? q : (p == 1) ? k : v;
        dst[((size_t)hh * SS + s) * HDD + d] = f2bf(val);
    }
}

// ---------------- flash attention, bf16 MFMA, fixed-max softmax, K-split ------
__global__ __launch_bounds__(256) void attn_mfma(
    const short* __restrict__ q, const short* __restrict__ k,
    const short* __restrict__ v, float* __restrict__ o_part,
    float* __restrict__ l_part)
{
    __shared__ short Ks[64][104];    // k-positions x d, pad cols 80..95 zeroed
    __shared__ short Vts[80][72];    // d x k-positions (transposed V)
    __shared__ short Ps[4][16][72];  // per-wave P tile

    const int h = blockIdx.y;
    const int q0 = blockIdx.x << 6;
    const int z = blockIdx.z;        // K-half
    const int tid = threadIdx.x;
    const int w = tid >> 6;
    const int lane = tid & 63;
    const int l15 = lane & 15;
    const int quad = lane >> 4;

    const short* qbase = q + (size_t)h * SS * HDD;
    const short* kbase = k + (size_t)h * SS * HDD;
    const short* vbase = v + (size_t)h * SS * HDD;

    short8 qf[3];
    {
        const int row = q0 + w * 16 + l15;
        #pragma unroll
        for (int kk = 0; kk < 3; ++kk) {
            int c0 = kk * 32 + quad * 8;
            qf[kk] = (c0 < HDD) ? *(const short8*)(qbase + (size_t)row * HDD + c0)
                                : (short8)0;
        }
    }

    if (tid < 128) {  // zero K pad cols 80..95
        int r = tid >> 1, c = 80 + (tid & 1) * 8;
        *(short8*)&Ks[r][c] = (short8)0;
    }

    float lsum[4] = {0.f, 0.f, 0.f, 0.f};
    f32x4 o[5];
    #pragma unroll
    for (int n = 0; n < 5; ++n) o[n] = (f32x4){0.f, 0.f, 0.f, 0.f};

    const int kt0 = z << 10;
    for (int kt = kt0; kt < kt0 + 1024; kt += 64) {
        __syncthreads();
        #pragma unroll
        for (int u = 0; u < 3; ++u) {
            int i = tid + u * 256;
            if (i < 640) {
                int r = i / 10, c = (i - r * 10) * 8;
                *(short8*)&Ks[r][c] = *(const short8*)(kbase + (size_t)(kt + r) * HDD + c);
            }
        }
        #pragma unroll
        for (int u = 0; u < 2; ++u) {
            int task = tid + u * 256;
            if (task < 320) {
                int r4 = (task & 15) << 2, d4 = (task >> 4) << 2;
                s16x4 a0 = *(const s16x4*)(vbase + (size_t)(kt + r4 + 0) * HDD + d4);
                s16x4 a1 = *(const s16x4*)(vbase + (size_t)(kt + r4 + 1) * HDD + d4);
                s16x4 a2 = *(const s16x4*)(vbase + (size_t)(kt + r4 + 2) * HDD + d4);
                s16x4 a3 = *(const s16x4*)(vbase + (size_t)(kt + r4 + 3) * HDD + d4);
                #pragma unroll
                for (int j = 0; j < 4; ++j) {
                    s16x4 w4 = {a0[j], a1[j], a2[j], a3[j]};
                    *(s16x4*)&Vts[d4 + j][r4] = w4;
                }
            }
        }
        __syncthreads();

        f32x4 s_[4];
        #pragma unroll
        for (int nt = 0; nt < 4; ++nt) {
            f32x4 acc = (f32x4){0.f, 0.f, 0.f, 0.f};
            #pragma unroll
            for (int kk = 0; kk < 3; ++kk) {
                short8 bf = *(short8*)&Ks[nt * 16 + l15][kk * 32 + quad * 8];
                acc = __builtin_amdgcn_mfma_f32_16x16x32_bf16(qf[kk], bf, acc, 0, 0, 0);
            }
            s_[nt] = acc;
        }

        #pragma unroll
        for (int nt = 0; nt < 4; ++nt)
            #pragma unroll
            for (int r = 0; r < 4; ++r) {
                float p = __expf(s_[nt][r] - 16.f);
                lsum[r] += p;
                Ps[w][quad * 4 + r][nt * 16 + l15] = f2bf(p);
            }

        short8 pf[2];
        #pragma unroll
        for (int kk = 0; kk < 2; ++kk)
            pf[kk] = *(short8*)&Ps[w][l15][kk * 32 + quad * 8];
        #pragma unroll
        for (int n = 0; n < 5; ++n)
            #pragma unroll
            for (int kk = 0; kk < 2; ++kk) {
                short8 vf = *(short8*)&Vts[n * 16 + l15][kk * 32 + quad * 8];
                o[n] = __builtin_amdgcn_mfma_f32_16x16x32_bf16(pf[kk], vf, o[n], 0, 0, 0);
            }
    }

    #pragma unroll
    for (int r = 0; r < 4; ++r) {
        float rs = lsum[r];
        #pragma unroll
        for (int off = 1; off < 16; off <<= 1)
            rs += __shfl_xor(rs, off, 64);
        lsum[r] = rs;
    }

    float* ob = o_part + (size_t)z * SS * DD;
    #pragma unroll
    for (int n = 0; n < 5; ++n)
        #pragma unroll
        for (int r = 0; r < 4; ++r) {
            int row = q0 + w * 16 + quad * 4 + r;
            ob[(size_t)row * DD + h * HDD + n * 16 + l15] = o[n][r];
        }
    if (l15 == 0)
        #pragma unroll
        for (int r = 0; r < 4; ++r)
            l_part[((size_t)z * HH + h) * SS + q0 + w * 16 + quad * 4 + r] = lsum[r];
}

// ---------------- merge K-split halves, emit hi/lo bf16 ----------------
__global__ __launch_bounds__(256) void attn_merge(
    const float* __restrict__ o_part, const float* __restrict__ l_part,
    short* __restrict__ hi, short* __restrict__ lo)
{
    int i = (blockIdx.x * 256 + threadIdx.x) * 4;
    int row = i / DD;
    int col = i - row * DD;
    int h = col / HDD;
    float4 a = *(const float4*)(o_part + i);
    float4 b = *(const float4*)(o_part + (size_t)SS * DD + i);
    float l = l_part[h * SS + row] + l_part[(HH + h) * SS + row];
    float inv = 1.f / l;
    float vv[4] = {a.x + b.x, a.y + b.y, a.z + b.z, a.w + b.w};
    s16x4 vh, vl;
    #pragma unroll
    for (int c = 0; c < 4; ++c) {
        float ov = vv[c] * inv;
        short hh = f2bf(ov);
        vh[c] = hh;
        vl[c] = f2bf(ov - bf2f(hh));
    }
    *(s16x4*)(hi + i) = vh;
    *(s16x4*)(lo + i) = vl;
}

extern "C" void kernel_launch(void* const* d_in, const int* in_sizes, int n_in,
                              void* d_out, int out_size, void* d_ws, size_t ws_size,
                              hipStream_t stream)
{
    const float* hs     = (const float*)d_in[0];
    const float* rpe    = (const float*)d_in[1];
    const float* qkv_w  = (const float*)d_in[2];
    const float* qkv_b  = (const float*)d_in[3];
    const float* proj_w = (const float*)d_in[4];
    const float* proj_b = (const float*)d_in[5];
    float* out = (float*)d_out;

    // ---- workspace layout (61.6 MB, region-aliased) ----
    short* s0 = (short*)d_ws;                 // R0: 15,728,640 shorts = 7,864,320 floats
    float* qkv_f  = (float*)d_ws;             //   [S][3D] fp32, dead after rope
    float* o_part = (float*)d_ws;             //   R0 reuse: 2 x S x D partial O
    float* l_part = (float*)d_ws + 5242880;   //   2 x H x S partial l
    short* s1 = s0 + 15728640;                // R1: 9,830,400 shorts
    short* qkvw_hi = s1;                      //   dead after gemm1
    short* qkvw_lo = s1 + 4915200;
    short* qb = s1;                           //   R1 reuse after gemm1 (dead after attn)
    short* kb = s1 + 2621440;
    short* vb = s1 + 5242880;
    short* attn_hi = s1;                      //   R1 reuse after attn (merge writes)
    short* attn_lo = s1 + 2621440;
    short* s2 = s1 + 9830400;                 // R2: 5,242,880 shorts
    short* hs_hi = s2;                        //   dead after gemm1
    short* hs_lo = s2 + 2621440;
    short* projw_hi = s2;                     //   R2 reuse after gemm1
    short* projw_lo = s2 + 1638400;

    const int n_hs = SS * DD;        // 2,621,440 -> 2560 blocks
    const int n_qw = ND3 * DD;       // 4,915,200 -> 4800 blocks
    const int n_pw = DD * DD;        // 1,638,400 -> 1600 blocks

    // NOTE: proj_w split must run BEFORE gemm1's region reuse is irrelevant —
    // projw lives in R2 which holds hs hi/lo until gemm1 completes. So split
    // hs+qkv_w first, then gemm1, then split proj_w into R2.
    split3<<<n_hs / 1024 + n_qw / 1024 + n_pw / 1024, 256, 0, stream>>>(
        hs, hs_hi, hs_lo, n_hs / 1024,
        qkv_w, qkvw_hi, qkvw_lo, n_qw / 1024,
        proj_w, (short*)d_ws, (short*)d_ws + 1638400);   // proj split staged in R0 (free now)
    gemm_bf16x3<128, 64><<<dim3(ND3 / 64, SS / 128), 256, 0, stream>>>(
        hs_hi, hs_lo, qkvw_hi, qkvw_lo, qkv_b, qkv_f, SS, ND3, DD);
    // qkv_f overwrote R0's proj split? NO — qkv_f IS R0. Re-split proj_w into R2
    // after gemm1 (hs hi/lo dead), cheap (1600 blocks).
    split3<<<n_pw / 1024, 256, 0, stream>>>(
        proj_w, projw_hi, projw_lo, n_pw / 1024,
        proj_w, projw_hi, projw_lo, 0,
        proj_w, projw_hi, projw_lo);
    rope_scatter_bf16<<<SS, 256, 0, stream>>>(qkv_f, rpe, qb, kb, vb);
    attn_mfma<<<dim3(SS / 64, HH, 2), 256, 0, stream>>>(qb, kb, vb, o_part, l_part);
    attn_merge<<<(SS * DD) / 1024, 256, 0, stream>>>(o_part, l_part, attn_hi, attn_lo);
    gemm_bf16x3<64, 64><<<dim3(DD / 64, SS / 64), 256, 0, stream>>>(
        attn_hi, attn_lo, projw_hi, projw_lo, proj_b, out, SS, DD, DD);
}